// Round 7
// baseline (74881.000 us; speedup 1.0000x reference)
//
#include <hip/hip_runtime.h>
#include <hip/hip_bf16.h>
#include <hip/hip_fp16.h>

typedef unsigned int u32;
typedef __fp16 h2t __attribute__((ext_vector_type(2)));

// ---------------- dims ----------------
#define T_STEPS_D 128
#define NBATCH 512

// ws layout (u32 element offsets). Weights f16, k-paired: W2[k/2][n] u32 = (f16 W[k][n], f16 W[k+1][n])
#define OFF_TWI   0L         // K2=278 (150 t_Wi + 128 t_Wh), N=1024
#define OFF_AWI   284672L    // K2=69 (37+32), N=256
#define OFF_VWI   302336L    // K2=50 (18+32), N=256
#define OFF_A1W1  315136L    // K2=384, N=512
#define OFF_A1W2  511744L    // K2=256, N=768
#define OFF_A2W1  708352L    // K2=384, N=512
#define OFF_A2W2  904960L    // K2=256, N=256
#define OFF_GW1   970496L    // K2=512, N=1024 (cols 0-511 g1_w1, 512-1023 g2_w1)
#define OFF_GW2   1494784L   // K2=256, N=512 (cols 0-255 g1_w2, 256-511 g2_w2)
#define OFF_OW1   1625856L   // K2=320, N=512
#define U32_TOTAL 1789696L   // u32 elements; fp32 packed biases follow (1536 floats)

__device__ __forceinline__ float sigm(float x) { return 1.f / (1.f + __expf(-x)); }
__device__ __forceinline__ float tanh_fast(float x) {
    float e = __expf(2.f * x);
    return 1.f - 2.f / (e + 1.f);
}
__device__ __forceinline__ float dot2(u32 a, u32 b, float c) {
    union { u32 u; h2t h; } x, y; x.u = a; y.u = b;
#if __has_builtin(__builtin_amdgcn_fdot2)
    return __builtin_amdgcn_fdot2(x.h, y.h, c, false);
#else
    c += (float)x.h[0] * (float)y.h[0];
    c += (float)x.h[1] * (float)y.h[1];
    return c;
#endif
}
__device__ __forceinline__ u32 pk2(float a, float b) {
    union { h2t h; u32 u; } z;
    z.h = __builtin_amdgcn_cvt_pkrtz(a, b);
    return z.u;
}

// ---- one weight block (8 k-pairs) of a GEMM part ----
__device__ __forceinline__ void gp_load(u32* buf, const u32* __restrict__ wp, int N) {
#pragma unroll
    for (int u = 0; u < 8; ++u) buf[u] = wp[u * N];
}
__device__ __forceinline__ void gp_compute(float* acc, const u32* __restrict__ a, int stA,
                                           int i, const u32* buf) {
#pragma unroll
    for (int r = 0; r < 4; ++r) {
        uint4 xa = *(const uint4*)(a + r * stA + i * 8);
        uint4 xb = *(const uint4*)(a + r * stA + i * 8 + 4);
        float s = acc[r];
        s = dot2(buf[0], xa.x, s); s = dot2(buf[1], xa.y, s);
        s = dot2(buf[2], xa.z, s); s = dot2(buf[3], xa.w, s);
        s = dot2(buf[4], xb.x, s); s = dot2(buf[5], xb.y, s);
        s = dot2(buf[6], xb.z, s); s = dot2(buf[7], xb.w, s);
        acc[r] = s;
    }
}

// One part of a GEMM: acc[r] += sum_k a[r][k]*W[k][n0]. w = WT + n0 (per-lane),
// rows advance by N. Depth-3 register prefetch pipeline, no scratch, no struct arrays.
__device__ __forceinline__ void gpart(float* acc, const u32* __restrict__ a, int k2, int stA,
                                      const u32* __restrict__ w, int N)
{
    const int nb = k2 >> 3;
    u32 b0[8], b1[8], b2[8];
    if (nb > 0) gp_load(b0, w, N);
    if (nb > 1) gp_load(b1, w + 8 * N, N);
    if (nb > 2) gp_load(b2, w + 16 * N, N);
    int i = 0;
    while (i < nb) {
        gp_compute(acc, a, stA, i, b0);
        if (i + 3 < nb) gp_load(b0, w + (i + 3) * 8 * N, N);
        ++i; if (i >= nb) break;
        gp_compute(acc, a, stA, i, b1);
        if (i + 3 < nb) gp_load(b1, w + (i + 3) * 8 * N, N);
        ++i; if (i >= nb) break;
        gp_compute(acc, a, stA, i, b2);
        if (i + 3 < nb) gp_load(b2, w + (i + 3) * 8 * N, N);
        ++i;
    }
    for (int k = nb * 8; k < k2; ++k) {   // tail
        u32 wv = w[k * N];
#pragma unroll
        for (int r = 0; r < 4; ++r) acc[r] = dot2(wv, a[r * stA + k], acc[r]);
    }
}

// -------- prologue kernels --------
__global__ void k_transpose(const float* __restrict__ src, unsigned short* __restrict__ dst,
                            int N, int K, int strideU, int rowOffK, int colOff)
{
    long i = (long)blockIdx.x * 256 + threadIdx.x;
    if (i >= (long)N * K) return;
    int n = (int)(i / K);
    int k = (int)(i - (long)n * K);
    __half h = __float2half(src[i]);
    int kk = k + rowOffK;
    long idx = (long)(kk >> 1) * (2L * strideU) + 2L * (colOff + n) + (kk & 1);
    dst[idx] = __half_as_ushort(h);
}

__global__ void k_packbias(const float* __restrict__ g1b1, const float* __restrict__ g2b1,
                           const float* __restrict__ g1b2, const float* __restrict__ g2b2,
                           float* __restrict__ gb)
{
    int i = blockIdx.x * 256 + threadIdx.x;
    if (i < 512) gb[i] = g1b1[i];
    else if (i < 1024) gb[i] = g2b1[i - 512];
    else if (i < 1280) gb[i] = g1b2[i - 1024];
    else if (i < 1536) gb[i] = g2b2[i - 1280];
}

// -------- main persistent kernel: one WG = 4 batch rows, 1024 threads, 128 WGs --------
// __launch_bounds__(1024) (NO min-waves arg): 16-wave block forces VGPR<=128 naturally;
// the explicit ",4" in round 6 drove the allocator to 64 VGPR -> catastrophic spill.
__global__ __launch_bounds__(1024)
void fused_rnn(const float* __restrict__ x_p,
               const float* __restrict__ c_t0, const float* __restrict__ c_a0,
               const float* __restrict__ c_v0, const float* __restrict__ mem0,
               const float* __restrict__ t_b, const float* __restrict__ a_b,
               const float* __restrict__ v_b,
               const float* __restrict__ a1b1, const float* __restrict__ a1b2,
               const float* __restrict__ a2b1, const float* __restrict__ a2b2,
               const float* __restrict__ ob1, const float* __restrict__ ow2,
               const float* __restrict__ ob2,
               const u32* __restrict__ wsu, const float* __restrict__ wsf,
               float* __restrict__ out)
{
    const int tid = threadIdx.x;
    const int row0 = blockIdx.x * 4;

    // fp32 buffers
    __shared__ alignas(16) float sZ[4][1024];     // t-LSTM z / attn1 scores
    __shared__ alignas(16) float sZa[4][256];
    __shared__ alignas(16) float sZv[4][256];
    __shared__ alignas(16) float sTc[4][256];
    __shared__ alignas(16) float sAc[4][64];
    __shared__ alignas(16) float sVc[4][64];
    __shared__ alignas(16) float sM[4][256];
    __shared__ alignas(16) float sCs[4][768];     // c_star fp32
    __shared__ alignas(16) float sG[4][512];      // [g1raw|g2raw]
    __shared__ alignas(16) float sCp[2][4][256];  // attn2-l2 split-K partials
    __shared__ alignas(16) float sPart[2][4][512];// split-K partials (attn1l1 / attn2l1)
    // packed f16-pair buffers
    __shared__ alignas(16) u32 pX[4][212];   // xt pairs 0-149, xa 152-188, xv 192-209
    __shared__ alignas(16) u32 pCs[4][384];  // c_star / attended
    __shared__ alignas(16) u32 pTh[4][128];
    __shared__ alignas(16) u32 pAh[4][32];
    __shared__ alignas(16) u32 pVh[4][32];
    __shared__ alignas(16) u32 pM[4][128];
    __shared__ alignas(16) u32 pHid[4][256];
    __shared__ alignas(16) u32 pZ[4][512];
    __shared__ float sRed[4];
    __shared__ float sRed2[8][4];

    // ---- init states ----
    if (tid < 512) {
        int r = tid >> 7, j2 = tid & 127, j = 2 * j2;
        float t0 = c_t0[(row0 + r) * 256 + j], t1 = c_t0[(row0 + r) * 256 + j + 1];
        float m0 = mem0[(row0 + r) * 256 + j], m1 = mem0[(row0 + r) * 256 + j + 1];
        sTc[r][j] = t0; sTc[r][j + 1] = t1;
        sM[r][j] = m0; sM[r][j + 1] = m1;
        pM[r][j2] = pk2(m0, m1);
        pTh[r][j2] = 0u;
    } else if (tid < 640) {
        int t2 = tid - 512;
        int r = t2 >> 5, j2 = t2 & 31, j = 2 * j2;
        sAc[r][j] = c_a0[(row0 + r) * 64 + j]; sAc[r][j + 1] = c_a0[(row0 + r) * 64 + j + 1];
        sVc[r][j] = c_v0[(row0 + r) * 64 + j]; sVc[r][j + 1] = c_v0[(row0 + r) * 64 + j + 1];
        pAh[r][j2] = 0u; pVh[r][j2] = 0u;
    }
    __syncthreads();

    for (int t = 0; t < T_STEPS_D; ++t) {
        // ---- stage 1: pack x, copy+pack pre_c ----
        const float* xb = x_p + ((long)t * NBATCH + row0) * 410;
        if (tid < 820) {
            int r = tid / 205, p = tid - r * 205;
            float2 v = *(const float2*)(xb + r * 410 + 2 * p);
            int dst = (p < 150) ? p : (p < 187 ? p + 2 : p + 5);
            pX[r][dst] = pk2(v.x, v.y);
        }
        if (tid < 768) {
            int r = tid / 192, p = tid - r * 192;
            float v0, v1; int c;
            if (p < 128) { c = 2 * p; v0 = sTc[r][c]; v1 = sTc[r][c + 1]; }
            else if (p < 160) { int j = 2 * (p - 128); c = 256 + j; v0 = sAc[r][j]; v1 = sAc[r][j + 1]; }
            else { int j = 2 * (p - 160); c = 320 + j; v0 = sVc[r][j]; v1 = sVc[r][j + 1]; }
            sCs[r][c] = v0; sCs[r][c + 1] = v1;
            pCs[r][p] = pk2(v0, v1);
        }
        __syncthreads();

        // ---- stage 2: LSTM pre-activations ----
        {   // t-LSTM: N=1024, all threads
            float acc[4] = {0.f, 0.f, 0.f, 0.f};
            gpart(acc, &pX[0][0], 150, 212, wsu + OFF_TWI + tid, 1024);
            gpart(acc, &pTh[0][0], 128, 128, wsu + OFF_TWI + 150L * 1024 + tid, 1024);
            float b = t_b[tid];
#pragma unroll
            for (int r = 0; r < 4; ++r) sZ[r][tid] = acc[r] + b;
        }
        if (tid < 256) {   // a-LSTM
            float acc[4] = {0.f, 0.f, 0.f, 0.f};
            gpart(acc, &pX[0][152], 37, 212, wsu + OFF_AWI + tid, 256);
            gpart(acc, &pAh[0][0], 32, 32, wsu + OFF_AWI + 37L * 256 + tid, 256);
            float b = a_b[tid];
#pragma unroll
            for (int r = 0; r < 4; ++r) sZa[r][tid] = acc[r] + b;
        } else if (tid < 512) {  // v-LSTM
            int st = tid - 256;
            float acc[4] = {0.f, 0.f, 0.f, 0.f};
            gpart(acc, &pX[0][192], 18, 212, wsu + OFF_VWI + st, 256);
            gpart(acc, &pVh[0][0], 32, 32, wsu + OFF_VWI + 18L * 256 + st, 256);
            float b = v_b[st];
#pragma unroll
            for (int r = 0; r < 4; ++r) sZv[r][st] = acc[r] + b;
        }
        __syncthreads();

        // ---- stage 3: LSTM pointwise (disjoint thread groups) ----
        if (tid < 512) {
            int r = tid >> 7, j2 = tid & 127, j = 2 * j2;
            float i0 = sZ[r][j], f0 = sZ[r][256 + j], g0 = sZ[r][512 + j], o0 = sZ[r][768 + j];
            float i1 = sZ[r][j + 1], f1 = sZ[r][257 + j], g1 = sZ[r][513 + j], o1 = sZ[r][769 + j];
            float c20 = sigm(f0) * sTc[r][j] + sigm(i0) * tanh_fast(g0);
            float c21 = sigm(f1) * sTc[r][j + 1] + sigm(i1) * tanh_fast(g1);
            float h20 = sigm(o0) * tanh_fast(c20);
            float h21 = sigm(o1) * tanh_fast(c21);
            sTc[r][j] = c20; sTc[r][j + 1] = c21;
            sCs[r][384 + j] = c20; sCs[r][385 + j] = c21;
            pTh[r][j2] = pk2(h20, h21);
            pCs[r][192 + j2] = pk2(c20, c21);
        } else if (tid < 640) {
            int t2 = tid - 512;
            int r = t2 >> 5, j2 = t2 & 31, j = 2 * j2;
            float i0 = sZa[r][j], f0 = sZa[r][64 + j], g0 = sZa[r][128 + j], o0 = sZa[r][192 + j];
            float i1 = sZa[r][j + 1], f1 = sZa[r][65 + j], g1 = sZa[r][129 + j], o1 = sZa[r][193 + j];
            float c20 = sigm(f0) * sAc[r][j] + sigm(i0) * tanh_fast(g0);
            float c21 = sigm(f1) * sAc[r][j + 1] + sigm(i1) * tanh_fast(g1);
            float h20 = sigm(o0) * tanh_fast(c20);
            float h21 = sigm(o1) * tanh_fast(c21);
            sAc[r][j] = c20; sAc[r][j + 1] = c21;
            sCs[r][640 + j] = c20; sCs[r][641 + j] = c21;
            pAh[r][j2] = pk2(h20, h21);
            pCs[r][320 + j2] = pk2(c20, c21);
        } else if (tid < 768) {
            int t2 = tid - 640;
            int r = t2 >> 5, j2 = t2 & 31, j = 2 * j2;
            float i0 = sZv[r][j], f0 = sZv[r][64 + j], g0 = sZv[r][128 + j], o0 = sZv[r][192 + j];
            float i1 = sZv[r][j + 1], f1 = sZv[r][65 + j], g1 = sZv[r][129 + j], o1 = sZv[r][193 + j];
            float c20 = sigm(f0) * sVc[r][j] + sigm(i0) * tanh_fast(g0);
            float c21 = sigm(f1) * sVc[r][j + 1] + sigm(i1) * tanh_fast(g1);
            float h20 = sigm(o0) * tanh_fast(c20);
            float h21 = sigm(o1) * tanh_fast(c21);
            sVc[r][j] = c20; sVc[r][j + 1] = c21;
            sCs[r][704 + j] = c20; sCs[r][705 + j] = c21;
            pVh[r][j2] = pk2(h20, h21);
            pCs[r][352 + j2] = pk2(c20, c21);
        }
        __syncthreads();

        // ---- stage 4a: attn1-l1 split-K (2 halves x 512 threads) ----
        {
            int half = tid >> 9, st = tid & 511;
            float acc[4] = {0.f, 0.f, 0.f, 0.f};
            gpart(acc, &pCs[0][half * 192], 192, 384,
                  wsu + OFF_A1W1 + (long)half * 192 * 512 + st, 512);
#pragma unroll
            for (int r = 0; r < 4; ++r) sPart[half][r][st] = acc[r];
        }
        __syncthreads();
        {   // combine + relu + pack -> pHid
            int r = tid >> 8, cp = tid & 255, c = 2 * cp;
            float v0 = fmaxf(sPart[0][r][c] + sPart[1][r][c] + a1b1[c], 0.f);
            float v1 = fmaxf(sPart[0][r][c + 1] + sPart[1][r][c + 1] + a1b1[c + 1], 0.f);
            pHid[r][cp] = pk2(v0, v1);
        }
        __syncthreads();

        // ---- stage 4b: attn1-l2 -> scores sZ ----
        if (tid < 768) {
            float acc[4] = {0.f, 0.f, 0.f, 0.f};
            gpart(acc, &pHid[0][0], 256, 256, wsu + OFF_A1W2 + tid, 768);
            float b = a1b2[tid];
#pragma unroll
            for (int r = 0; r < 4; ++r) sZ[r][tid] = acc[r] + b;
        }
        __syncthreads();

        // ---- stage 5: softmax (4 waves) ----
        {
            int wv = tid >> 6, ln = tid & 63;
            if (wv < 4) {
                float mx = -3.0e38f;
                for (int i = ln; i < 768; i += 64) mx = fmaxf(mx, sZ[wv][i]);
                for (int o = 32; o; o >>= 1) mx = fmaxf(mx, __shfl_xor(mx, o));
                float sum = 0.f;
                for (int i = ln; i < 768; i += 64) { float e = __expf(sZ[wv][i] - mx); sZ[wv][i] = e; sum += e; }
                for (int o = 32; o; o >>= 1) sum += __shfl_xor(sum, o);
                if (ln == 0) sRed[wv] = 1.f / sum;
            }
        }
        __syncthreads();
        for (int i = tid; i < 1536; i += 1024) {   // attended -> pCs
            int r = i / 384, p = i - r * 384, c = 2 * p;
            float s = sRed[r];
            pCs[r][p] = pk2(sZ[r][c] * s * sCs[r][c], sZ[r][c + 1] * s * sCs[r][c + 1]);
        }
        __syncthreads();

        // ---- stage 6: gates-l1 (all, N=1024, packed out) ; attn2-l1 split-K ----
        {
            float acc[4] = {0.f, 0.f, 0.f, 0.f};
            gpart(acc, &pCs[0][0], 384, 384, wsu + OFF_GW1 + tid, 1024);
            gpart(acc, &pM[0][0], 128, 128, wsu + OFF_GW1 + 384L * 1024 + tid, 1024);
            float b = wsf[tid];
            float v[4];
#pragma unroll
            for (int r = 0; r < 4; ++r) v[r] = fmaxf(acc[r] + b, 0.f);
#pragma unroll
            for (int r = 0; r < 4; ++r) {
                float vo = __shfl_xor(v[r], 1);
                if (!(tid & 1)) pZ[r][tid >> 1] = pk2(v[r], vo);
            }
        }
        {
            int half = tid >> 9, st = tid & 511;
            float acc[4] = {0.f, 0.f, 0.f, 0.f};
            gpart(acc, &pCs[0][half * 192], 192, 384,
                  wsu + OFF_A2W1 + (long)half * 192 * 512 + st, 512);
#pragma unroll
            for (int r = 0; r < 4; ++r) sPart[half][r][st] = acc[r];
        }
        __syncthreads();
        {   // combine attn2-l1 -> pHid
            int r = tid >> 8, cp = tid & 255, c = 2 * cp;
            float v0 = fmaxf(sPart[0][r][c] + sPart[1][r][c] + a2b1[c], 0.f);
            float v1 = fmaxf(sPart[0][r][c + 1] + sPart[1][r][c + 1] + a2b1[c + 1], 0.f);
            pHid[r][cp] = pk2(v0, v1);
        }
        __syncthreads();

        // ---- stage 7: gates-l2 (tid<512) ; attn2-l2 split-K (tid>=512) ----
        if (tid < 512) {
            float acc[4] = {0.f, 0.f, 0.f, 0.f};
            gpart(acc, &pZ[0][0], 256, 512, wsu + OFF_GW2 + tid, 512);
            float b = wsf[1024 + tid];
#pragma unroll
            for (int r = 0; r < 4; ++r) sG[r][tid] = acc[r] + b;
        } else {
            int t2 = tid - 512, kh = t2 >> 8, col = t2 & 255;
            float acc[4] = {0.f, 0.f, 0.f, 0.f};
            gpart(acc, &pHid[0][kh * 128], 128, 256,
                  wsu + OFF_A2W2 + (long)kh * 128 * 256 + col, 256);
#pragma unroll
            for (int r = 0; r < 4; ++r) sCp[kh][r][col] = acc[r];
        }
        __syncthreads();

        // ---- stage 8: memory update ----
        if (tid < 512) {
            int r = tid >> 7, j2 = tid & 127, j = 2 * j2;
            float g10 = sigm(sG[r][j]),       g11 = sigm(sG[r][j + 1]);
            float g20 = sigm(sG[r][256 + j]), g21 = sigm(sG[r][257 + j]);
            float ch0 = tanh_fast(sCp[0][r][j] + sCp[1][r][j] + a2b2[j]);
            float ch1 = tanh_fast(sCp[0][r][j + 1] + sCp[1][r][j + 1] + a2b2[j + 1]);
            float m0 = g10 * sM[r][j] + g20 * ch0;
            float m1 = g11 * sM[r][j + 1] + g21 * ch1;
            sM[r][j] = m0; sM[r][j + 1] = m1;
            pM[r][j2] = pk2(m0, m1);
        }
        __syncthreads();
    }

    // ---- output head: last_h = [th, ah, vh, m] ----
    if (tid < 512) {
        float acc[4] = {0.f, 0.f, 0.f, 0.f};
        gpart(acc, &pTh[0][0], 128, 128, wsu + OFF_OW1 + tid, 512);
        gpart(acc, &pAh[0][0], 32, 32, wsu + OFF_OW1 + 128L * 512 + tid, 512);
        gpart(acc, &pVh[0][0], 32, 32, wsu + OFF_OW1 + 160L * 512 + tid, 512);
        gpart(acc, &pM[0][0], 128, 128, wsu + OFF_OW1 + 192L * 512 + tid, 512);
        float b = ob1[tid], w2 = ow2[tid];
        float pr[4];
#pragma unroll
        for (int r = 0; r < 4; ++r) pr[r] = fmaxf(acc[r] + b, 0.f) * w2;
#pragma unroll
        for (int o = 32; o; o >>= 1) {
#pragma unroll
            for (int r = 0; r < 4; ++r) pr[r] += __shfl_xor(pr[r], o);
        }
        int wvid = tid >> 6, ln = tid & 63;
        if (ln == 0) {
#pragma unroll
            for (int r = 0; r < 4; ++r) sRed2[wvid][r] = pr[r];
        }
    }
    __syncthreads();
    if (tid < 4) {
        float s = 0.f;
#pragma unroll
        for (int w = 0; w < 8; ++w) s += sRed2[w][tid];
        out[row0 + tid] = s + ob2[0];
    }
}

extern "C" void kernel_launch(void* const* d_in, const int* in_sizes, int n_in,
                              void* d_out, int out_size, void* d_ws, size_t ws_size,
                              hipStream_t stream)
{
    const float* x_p  = (const float*)d_in[0];
    const float* c_t  = (const float*)d_in[1];
    const float* c_a  = (const float*)d_in[2];
    const float* c_v  = (const float*)d_in[3];
    const float* memp = (const float*)d_in[4];

    u32* wsu = (u32*)d_ws;
    float* wsf = (float*)((char*)d_ws + (size_t)U32_TOTAL * 4);
    // total ws use: ~7.17 MB

    auto T = [&](const void* src, long off, int N, int K, int strideU, int rowOffK, int colOff) {
        long total = (long)N * K;
        int blocks = (int)((total + 255) / 256);
        hipLaunchKernelGGL(k_transpose, dim3(blocks), dim3(256), 0, stream,
                           (const float*)src, (unsigned short*)(wsu + off), N, K, strideU, rowOffK, colOff);
    };
    T(d_in[5],  OFF_TWI,  1024, 300, 1024, 0,   0);   // t_Wi
    T(d_in[6],  OFF_TWI,  1024, 256, 1024, 300, 0);   // t_Wh
    T(d_in[8],  OFF_AWI,  256,  74,  256,  0,   0);   // a_Wi
    T(d_in[9],  OFF_AWI,  256,  64,  256,  74,  0);   // a_Wh
    T(d_in[11], OFF_VWI,  256,  36,  256,  0,   0);   // v_Wi
    T(d_in[12], OFF_VWI,  256,  64,  256,  36,  0);   // v_Wh
    T(d_in[14], OFF_A1W1, 512,  768, 512,  0,   0);   // attn1_w1
    T(d_in[16], OFF_A1W2, 768,  512, 768,  0,   0);   // attn1_w2
    T(d_in[18], OFF_A2W1, 512,  768, 512,  0,   0);   // attn2_w1
    T(d_in[20], OFF_A2W2, 256,  512, 256,  0,   0);   // attn2_w2
    T(d_in[22], OFF_GW1,  512, 1024, 1024, 0,   0);   // g1_w1 -> cols 0-511
    T(d_in[26], OFF_GW1,  512, 1024, 1024, 0,   512); // g2_w1 -> cols 512-1023
    T(d_in[24], OFF_GW2,  256,  512, 512,  0,   0);   // g1_w2 -> cols 0-255
    T(d_in[28], OFF_GW2,  256,  512, 512,  0,   256); // g2_w2 -> cols 256-511
    T(d_in[30], OFF_OW1,  512,  640, 512,  0,   0);   // out_w1

    hipLaunchKernelGGL(k_packbias, dim3(6), dim3(256), 0, stream,
                       (const float*)d_in[23], (const float*)d_in[27],
                       (const float*)d_in[25], (const float*)d_in[29], wsf);

    hipLaunchKernelGGL(fused_rnn, dim3(128), dim3(1024), 0, stream,
                       x_p, c_t, c_a, c_v, memp,
                       (const float*)d_in[7],  (const float*)d_in[10], (const float*)d_in[13],
                       (const float*)d_in[15], (const float*)d_in[17],
                       (const float*)d_in[19], (const float*)d_in[21],
                       (const float*)d_in[31], (const float*)d_in[32], (const float*)d_in[33],
                       wsu, wsf, (float*)d_out);
}

// Round 8
// 74569.342 us; speedup vs baseline: 1.0042x; 1.0042x over previous
//
#include <hip/hip_runtime.h>
#include <hip/hip_bf16.h>
#include <hip/hip_fp16.h>

typedef unsigned int u32;
typedef __fp16 h2t __attribute__((ext_vector_type(2)));

// ---------------- dims ----------------
#define T_STEPS_D 128
#define NBATCH 512

// ws layout (u32 element offsets). Weights f16, k-paired: W2[k/2][n] u32 = (f16 W[k][n], f16 W[k+1][n])
#define OFF_TWI   0L         // K2=278 (150 t_Wi + 128 t_Wh), N=1024
#define OFF_AWI   284672L    // K2=69 (37+32), N=256
#define OFF_VWI   302336L    // K2=50 (18+32), N=256
#define OFF_A1W1  315136L    // K2=384, N=512
#define OFF_A1W2  511744L    // K2=256, N=768
#define OFF_A2W1  708352L    // K2=384, N=512
#define OFF_A2W2  904960L    // K2=256, N=256
#define OFF_GW1   970496L    // K2=512, N=1024 (cols 0-511 g1_w1, 512-1023 g2_w1)
#define OFF_GW2   1494784L   // K2=256, N=512 (cols 0-255 g1_w2, 256-511 g2_w2)
#define OFF_OW1   1625856L   // K2=320, N=512
#define U32_TOTAL 1789696L   // u32 elements; fp32 packed biases follow (1536 floats)

__device__ __forceinline__ float sigm(float x) { return 1.f / (1.f + __expf(-x)); }
__device__ __forceinline__ float tanh_fast(float x) {
    float e = __expf(2.f * x);
    return 1.f - 2.f / (e + 1.f);
}
__device__ __forceinline__ float dot2(u32 a, u32 b, float c) {
    union { u32 u; h2t h; } x, y; x.u = a; y.u = b;
#if __has_builtin(__builtin_amdgcn_fdot2)
    return __builtin_amdgcn_fdot2(x.h, y.h, c, false);
#else
    c += (float)x.h[0] * (float)y.h[0];
    c += (float)x.h[1] * (float)y.h[1];
    return c;
#endif
}
__device__ __forceinline__ u32 pk2(float a, float b) {
    union { h2t h; u32 u; } z;
    z.h = __builtin_amdgcn_cvt_pkrtz(a, b);
    return z.u;
}

// ---- one weight block (8 k-pairs) of a GEMM part ----
__device__ __forceinline__ void gp_load(u32* buf, const u32* __restrict__ wp, int N) {
#pragma unroll
    for (int u = 0; u < 8; ++u) buf[u] = wp[u * N];
}
__device__ __forceinline__ void gp_compute(float* acc, const u32* __restrict__ a, int stA,
                                           int i, const u32* buf) {
#pragma unroll
    for (int r = 0; r < 4; ++r) {
        uint4 xa = *(const uint4*)(a + r * stA + i * 8);
        uint4 xb = *(const uint4*)(a + r * stA + i * 8 + 4);
        float s = acc[r];
        s = dot2(buf[0], xa.x, s); s = dot2(buf[1], xa.y, s);
        s = dot2(buf[2], xa.z, s); s = dot2(buf[3], xa.w, s);
        s = dot2(buf[4], xb.x, s); s = dot2(buf[5], xb.y, s);
        s = dot2(buf[6], xb.z, s); s = dot2(buf[7], xb.w, s);
        acc[r] = s;
    }
}

// One part of a GEMM: acc[r] += sum_k a[r][k]*W[k][n0]. w = WT + n0 (per-lane),
// rows advance by N. Depth-3 register prefetch pipeline, no scratch, no struct arrays.
__device__ __forceinline__ void gpart(float* acc, const u32* __restrict__ a, int k2, int stA,
                                      const u32* __restrict__ w, int N)
{
    const int nb = k2 >> 3;
    u32 b0[8], b1[8], b2[8];
    if (nb > 0) gp_load(b0, w, N);
    if (nb > 1) gp_load(b1, w + 8 * N, N);
    if (nb > 2) gp_load(b2, w + 16 * N, N);
    int i = 0;
    while (i < nb) {
        gp_compute(acc, a, stA, i, b0);
        if (i + 3 < nb) gp_load(b0, w + (i + 3) * 8 * N, N);
        ++i; if (i >= nb) break;
        gp_compute(acc, a, stA, i, b1);
        if (i + 3 < nb) gp_load(b1, w + (i + 3) * 8 * N, N);
        ++i; if (i >= nb) break;
        gp_compute(acc, a, stA, i, b2);
        if (i + 3 < nb) gp_load(b2, w + (i + 3) * 8 * N, N);
        ++i;
    }
    for (int k = nb * 8; k < k2; ++k) {   // tail
        u32 wv = w[k * N];
#pragma unroll
        for (int r = 0; r < 4; ++r) acc[r] = dot2(wv, a[r * stA + k], acc[r]);
    }
}

// -------- prologue kernels --------
__global__ void k_transpose(const float* __restrict__ src, unsigned short* __restrict__ dst,
                            int N, int K, int strideU, int rowOffK, int colOff)
{
    long i = (long)blockIdx.x * 256 + threadIdx.x;
    if (i >= (long)N * K) return;
    int n = (int)(i / K);
    int k = (int)(i - (long)n * K);
    __half h = __float2half(src[i]);
    int kk = k + rowOffK;
    long idx = (long)(kk >> 1) * (2L * strideU) + 2L * (colOff + n) + (kk & 1);
    dst[idx] = __half_as_ushort(h);
}

__global__ void k_packbias(const float* __restrict__ g1b1, const float* __restrict__ g2b1,
                           const float* __restrict__ g1b2, const float* __restrict__ g2b2,
                           float* __restrict__ gb)
{
    int i = blockIdx.x * 256 + threadIdx.x;
    if (i < 512) gb[i] = g1b1[i];
    else if (i < 1024) gb[i] = g2b1[i - 512];
    else if (i < 1280) gb[i] = g1b2[i - 1024];
    else if (i < 1536) gb[i] = g2b2[i - 1280];
}

// -------- main persistent kernel: one WG = 4 batch rows, 1024 threads, 128 WGs --------
// LDS (~104.5 KB) already limits to 1 WG/CU = 4 waves/SIMD. amdgpu_waves_per_eu(4,4)
// pins the allocator's occupancy target to that reality -> 128-VGPR budget. R6/R7 showed
// the default heuristic targets 8 waves/EU (64 VGPR) and spills ~35 GB/launch.
__global__
__attribute__((amdgpu_flat_work_group_size(1024, 1024)))
__attribute__((amdgpu_waves_per_eu(4, 4)))
void fused_rnn(const float* __restrict__ x_p,
               const float* __restrict__ c_t0, const float* __restrict__ c_a0,
               const float* __restrict__ c_v0, const float* __restrict__ mem0,
               const float* __restrict__ t_b, const float* __restrict__ a_b,
               const float* __restrict__ v_b,
               const float* __restrict__ a1b1, const float* __restrict__ a1b2,
               const float* __restrict__ a2b1, const float* __restrict__ a2b2,
               const float* __restrict__ ob1, const float* __restrict__ ow2,
               const float* __restrict__ ob2,
               const u32* __restrict__ wsu, const float* __restrict__ wsf,
               float* __restrict__ out)
{
    const int tid = threadIdx.x;
    const int row0 = blockIdx.x * 4;

    // fp32 buffers
    __shared__ alignas(16) float sZ[4][1024];     // t-LSTM z / attn1 scores
    __shared__ alignas(16) float sZa[4][256];
    __shared__ alignas(16) float sZv[4][256];
    __shared__ alignas(16) float sTc[4][256];
    __shared__ alignas(16) float sAc[4][64];
    __shared__ alignas(16) float sVc[4][64];
    __shared__ alignas(16) float sM[4][256];
    __shared__ alignas(16) float sCs[4][768];     // c_star fp32
    __shared__ alignas(16) float sG[4][512];      // [g1raw|g2raw]
    __shared__ alignas(16) float sCp[2][4][256];  // attn2-l2 split-K partials
    __shared__ alignas(16) float sPart[2][4][512];// split-K partials (attn1l1 / attn2l1)
    // packed f16-pair buffers
    __shared__ alignas(16) u32 pX[4][212];   // xt pairs 0-149, xa 152-188, xv 192-209
    __shared__ alignas(16) u32 pCs[4][384];  // c_star / attended
    __shared__ alignas(16) u32 pTh[4][128];
    __shared__ alignas(16) u32 pAh[4][32];
    __shared__ alignas(16) u32 pVh[4][32];
    __shared__ alignas(16) u32 pM[4][128];
    __shared__ alignas(16) u32 pHid[4][256];
    __shared__ alignas(16) u32 pZ[4][512];
    __shared__ float sRed[4];
    __shared__ float sRed2[8][4];

    // ---- init states ----
    if (tid < 512) {
        int r = tid >> 7, j2 = tid & 127, j = 2 * j2;
        float t0 = c_t0[(row0 + r) * 256 + j], t1 = c_t0[(row0 + r) * 256 + j + 1];
        float m0 = mem0[(row0 + r) * 256 + j], m1 = mem0[(row0 + r) * 256 + j + 1];
        sTc[r][j] = t0; sTc[r][j + 1] = t1;
        sM[r][j] = m0; sM[r][j + 1] = m1;
        pM[r][j2] = pk2(m0, m1);
        pTh[r][j2] = 0u;
    } else if (tid < 640) {
        int t2 = tid - 512;
        int r = t2 >> 5, j2 = t2 & 31, j = 2 * j2;
        sAc[r][j] = c_a0[(row0 + r) * 64 + j]; sAc[r][j + 1] = c_a0[(row0 + r) * 64 + j + 1];
        sVc[r][j] = c_v0[(row0 + r) * 64 + j]; sVc[r][j + 1] = c_v0[(row0 + r) * 64 + j + 1];
        pAh[r][j2] = 0u; pVh[r][j2] = 0u;
    }
    __syncthreads();

    for (int t = 0; t < T_STEPS_D; ++t) {
        // ---- stage 1: pack x, copy+pack pre_c ----
        const float* xb = x_p + ((long)t * NBATCH + row0) * 410;
        if (tid < 820) {
            int r = tid / 205, p = tid - r * 205;
            float2 v = *(const float2*)(xb + r * 410 + 2 * p);
            int dst = (p < 150) ? p : (p < 187 ? p + 2 : p + 5);
            pX[r][dst] = pk2(v.x, v.y);
        }
        if (tid < 768) {
            int r = tid / 192, p = tid - r * 192;
            float v0, v1; int c;
            if (p < 128) { c = 2 * p; v0 = sTc[r][c]; v1 = sTc[r][c + 1]; }
            else if (p < 160) { int j = 2 * (p - 128); c = 256 + j; v0 = sAc[r][j]; v1 = sAc[r][j + 1]; }
            else { int j = 2 * (p - 160); c = 320 + j; v0 = sVc[r][j]; v1 = sVc[r][j + 1]; }
            sCs[r][c] = v0; sCs[r][c + 1] = v1;
            pCs[r][p] = pk2(v0, v1);
        }
        __syncthreads();

        // ---- stage 2: LSTM pre-activations ----
        {   // t-LSTM: N=1024, all threads
            float acc[4] = {0.f, 0.f, 0.f, 0.f};
            gpart(acc, &pX[0][0], 150, 212, wsu + OFF_TWI + tid, 1024);
            gpart(acc, &pTh[0][0], 128, 128, wsu + OFF_TWI + 150L * 1024 + tid, 1024);
            float b = t_b[tid];
#pragma unroll
            for (int r = 0; r < 4; ++r) sZ[r][tid] = acc[r] + b;
        }
        if (tid < 256) {   // a-LSTM
            float acc[4] = {0.f, 0.f, 0.f, 0.f};
            gpart(acc, &pX[0][152], 37, 212, wsu + OFF_AWI + tid, 256);
            gpart(acc, &pAh[0][0], 32, 32, wsu + OFF_AWI + 37L * 256 + tid, 256);
            float b = a_b[tid];
#pragma unroll
            for (int r = 0; r < 4; ++r) sZa[r][tid] = acc[r] + b;
        } else if (tid < 512) {  // v-LSTM
            int st = tid - 256;
            float acc[4] = {0.f, 0.f, 0.f, 0.f};
            gpart(acc, &pX[0][192], 18, 212, wsu + OFF_VWI + st, 256);
            gpart(acc, &pVh[0][0], 32, 32, wsu + OFF_VWI + 18L * 256 + st, 256);
            float b = v_b[st];
#pragma unroll
            for (int r = 0; r < 4; ++r) sZv[r][st] = acc[r] + b;
        }
        __syncthreads();

        // ---- stage 3: LSTM pointwise (disjoint thread groups) ----
        if (tid < 512) {
            int r = tid >> 7, j2 = tid & 127, j = 2 * j2;
            float i0 = sZ[r][j], f0 = sZ[r][256 + j], g0 = sZ[r][512 + j], o0 = sZ[r][768 + j];
            float i1 = sZ[r][j + 1], f1 = sZ[r][257 + j], g1 = sZ[r][513 + j], o1 = sZ[r][769 + j];
            float c20 = sigm(f0) * sTc[r][j] + sigm(i0) * tanh_fast(g0);
            float c21 = sigm(f1) * sTc[r][j + 1] + sigm(i1) * tanh_fast(g1);
            float h20 = sigm(o0) * tanh_fast(c20);
            float h21 = sigm(o1) * tanh_fast(c21);
            sTc[r][j] = c20; sTc[r][j + 1] = c21;
            sCs[r][384 + j] = c20; sCs[r][385 + j] = c21;
            pTh[r][j2] = pk2(h20, h21);
            pCs[r][192 + j2] = pk2(c20, c21);
        } else if (tid < 640) {
            int t2 = tid - 512;
            int r = t2 >> 5, j2 = t2 & 31, j = 2 * j2;
            float i0 = sZa[r][j], f0 = sZa[r][64 + j], g0 = sZa[r][128 + j], o0 = sZa[r][192 + j];
            float i1 = sZa[r][j + 1], f1 = sZa[r][65 + j], g1 = sZa[r][129 + j], o1 = sZa[r][193 + j];
            float c20 = sigm(f0) * sAc[r][j] + sigm(i0) * tanh_fast(g0);
            float c21 = sigm(f1) * sAc[r][j + 1] + sigm(i1) * tanh_fast(g1);
            float h20 = sigm(o0) * tanh_fast(c20);
            float h21 = sigm(o1) * tanh_fast(c21);
            sAc[r][j] = c20; sAc[r][j + 1] = c21;
            sCs[r][640 + j] = c20; sCs[r][641 + j] = c21;
            pAh[r][j2] = pk2(h20, h21);
            pCs[r][320 + j2] = pk2(c20, c21);
        } else if (tid < 768) {
            int t2 = tid - 640;
            int r = t2 >> 5, j2 = t2 & 31, j = 2 * j2;
            float i0 = sZv[r][j], f0 = sZv[r][64 + j], g0 = sZv[r][128 + j], o0 = sZv[r][192 + j];
            float i1 = sZv[r][j + 1], f1 = sZv[r][65 + j], g1 = sZv[r][129 + j], o1 = sZv[r][193 + j];
            float c20 = sigm(f0) * sVc[r][j] + sigm(i0) * tanh_fast(g0);
            float c21 = sigm(f1) * sVc[r][j + 1] + sigm(i1) * tanh_fast(g1);
            float h20 = sigm(o0) * tanh_fast(c20);
            float h21 = sigm(o1) * tanh_fast(c21);
            sVc[r][j] = c20; sVc[r][j + 1] = c21;
            sCs[r][704 + j] = c20; sCs[r][705 + j] = c21;
            pVh[r][j2] = pk2(h20, h21);
            pCs[r][352 + j2] = pk2(c20, c21);
        }
        __syncthreads();

        // ---- stage 4a: attn1-l1 split-K (2 halves x 512 threads) ----
        {
            int half = tid >> 9, st = tid & 511;
            float acc[4] = {0.f, 0.f, 0.f, 0.f};
            gpart(acc, &pCs[0][half * 192], 192, 384,
                  wsu + OFF_A1W1 + (long)half * 192 * 512 + st, 512);
#pragma unroll
            for (int r = 0; r < 4; ++r) sPart[half][r][st] = acc[r];
        }
        __syncthreads();
        {   // combine + relu + pack -> pHid
            int r = tid >> 8, cp = tid & 255, c = 2 * cp;
            float v0 = fmaxf(sPart[0][r][c] + sPart[1][r][c] + a1b1[c], 0.f);
            float v1 = fmaxf(sPart[0][r][c + 1] + sPart[1][r][c + 1] + a1b1[c + 1], 0.f);
            pHid[r][cp] = pk2(v0, v1);
        }
        __syncthreads();

        // ---- stage 4b: attn1-l2 -> scores sZ ----
        if (tid < 768) {
            float acc[4] = {0.f, 0.f, 0.f, 0.f};
            gpart(acc, &pHid[0][0], 256, 256, wsu + OFF_A1W2 + tid, 768);
            float b = a1b2[tid];
#pragma unroll
            for (int r = 0; r < 4; ++r) sZ[r][tid] = acc[r] + b;
        }
        __syncthreads();

        // ---- stage 5: softmax (4 waves) ----
        {
            int wv = tid >> 6, ln = tid & 63;
            if (wv < 4) {
                float mx = -3.0e38f;
                for (int i = ln; i < 768; i += 64) mx = fmaxf(mx, sZ[wv][i]);
                for (int o = 32; o; o >>= 1) mx = fmaxf(mx, __shfl_xor(mx, o));
                float sum = 0.f;
                for (int i = ln; i < 768; i += 64) { float e = __expf(sZ[wv][i] - mx); sZ[wv][i] = e; sum += e; }
                for (int o = 32; o; o >>= 1) sum += __shfl_xor(sum, o);
                if (ln == 0) sRed[wv] = 1.f / sum;
            }
        }
        __syncthreads();
        for (int i = tid; i < 1536; i += 1024) {   // attended -> pCs
            int r = i / 384, p = i - r * 384, c = 2 * p;
            float s = sRed[r];
            pCs[r][p] = pk2(sZ[r][c] * s * sCs[r][c], sZ[r][c + 1] * s * sCs[r][c + 1]);
        }
        __syncthreads();

        // ---- stage 6: gates-l1 (all, N=1024, packed out) ; attn2-l1 split-K ----
        {
            float acc[4] = {0.f, 0.f, 0.f, 0.f};
            gpart(acc, &pCs[0][0], 384, 384, wsu + OFF_GW1 + tid, 1024);
            gpart(acc, &pM[0][0], 128, 128, wsu + OFF_GW1 + 384L * 1024 + tid, 1024);
            float b = wsf[tid];
            float v[4];
#pragma unroll
            for (int r = 0; r < 4; ++r) v[r] = fmaxf(acc[r] + b, 0.f);
#pragma unroll
            for (int r = 0; r < 4; ++r) {
                float vo = __shfl_xor(v[r], 1);
                if (!(tid & 1)) pZ[r][tid >> 1] = pk2(v[r], vo);
            }
        }
        {
            int half = tid >> 9, st = tid & 511;
            float acc[4] = {0.f, 0.f, 0.f, 0.f};
            gpart(acc, &pCs[0][half * 192], 192, 384,
                  wsu + OFF_A2W1 + (long)half * 192 * 512 + st, 512);
#pragma unroll
            for (int r = 0; r < 4; ++r) sPart[half][r][st] = acc[r];
        }
        __syncthreads();
        {   // combine attn2-l1 -> pHid
            int r = tid >> 8, cp = tid & 255, c = 2 * cp;
            float v0 = fmaxf(sPart[0][r][c] + sPart[1][r][c] + a2b1[c], 0.f);
            float v1 = fmaxf(sPart[0][r][c + 1] + sPart[1][r][c + 1] + a2b1[c + 1], 0.f);
            pHid[r][cp] = pk2(v0, v1);
        }
        __syncthreads();

        // ---- stage 7: gates-l2 (tid<512) ; attn2-l2 split-K (tid>=512) ----
        if (tid < 512) {
            float acc[4] = {0.f, 0.f, 0.f, 0.f};
            gpart(acc, &pZ[0][0], 256, 512, wsu + OFF_GW2 + tid, 512);
            float b = wsf[1024 + tid];
#pragma unroll
            for (int r = 0; r < 4; ++r) sG[r][tid] = acc[r] + b;
        } else {
            int t2 = tid - 512, kh = t2 >> 8, col = t2 & 255;
            float acc[4] = {0.f, 0.f, 0.f, 0.f};
            gpart(acc, &pHid[0][kh * 128], 128, 256,
                  wsu + OFF_A2W2 + (long)kh * 128 * 256 + col, 256);
#pragma unroll
            for (int r = 0; r < 4; ++r) sCp[kh][r][col] = acc[r];
        }
        __syncthreads();

        // ---- stage 8: memory update ----
        if (tid < 512) {
            int r = tid >> 7, j2 = tid & 127, j = 2 * j2;
            float g10 = sigm(sG[r][j]),       g11 = sigm(sG[r][j + 1]);
            float g20 = sigm(sG[r][256 + j]), g21 = sigm(sG[r][257 + j]);
            float ch0 = tanh_fast(sCp[0][r][j] + sCp[1][r][j] + a2b2[j]);
            float ch1 = tanh_fast(sCp[0][r][j + 1] + sCp[1][r][j + 1] + a2b2[j + 1]);
            float m0 = g10 * sM[r][j] + g20 * ch0;
            float m1 = g11 * sM[r][j + 1] + g21 * ch1;
            sM[r][j] = m0; sM[r][j + 1] = m1;
            pM[r][j2] = pk2(m0, m1);
        }
        __syncthreads();
    }

    // ---- output head: last_h = [th, ah, vh, m] ----
    if (tid < 512) {
        float acc[4] = {0.f, 0.f, 0.f, 0.f};
        gpart(acc, &pTh[0][0], 128, 128, wsu + OFF_OW1 + tid, 512);
        gpart(acc, &pAh[0][0], 32, 32, wsu + OFF_OW1 + 128L * 512 + tid, 512);
        gpart(acc, &pVh[0][0], 32, 32, wsu + OFF_OW1 + 160L * 512 + tid, 512);
        gpart(acc, &pM[0][0], 128, 128, wsu + OFF_OW1 + 192L * 512 + tid, 512);
        float b = ob1[tid], w2 = ow2[tid];
        float pr[4];
#pragma unroll
        for (int r = 0; r < 4; ++r) pr[r] = fmaxf(acc[r] + b, 0.f) * w2;
#pragma unroll
        for (int o = 32; o; o >>= 1) {
#pragma unroll
            for (int r = 0; r < 4; ++r) pr[r] += __shfl_xor(pr[r], o);
        }
        int wvid = tid >> 6, ln = tid & 63;
        if (ln == 0) {
#pragma unroll
            for (int r = 0; r < 4; ++r) sRed2[wvid][r] = pr[r];
        }
    }
    __syncthreads();
    if (tid < 4) {
        float s = 0.f;
#pragma unroll
        for (int w = 0; w < 8; ++w) s += sRed2[w][tid];
        out[row0 + tid] = s + ob2[0];
    }
}

extern "C" void kernel_launch(void* const* d_in, const int* in_sizes, int n_in,
                              void* d_out, int out_size, void* d_ws, size_t ws_size,
                              hipStream_t stream)
{
    const float* x_p  = (const float*)d_in[0];
    const float* c_t  = (const float*)d_in[1];
    const float* c_a  = (const float*)d_in[2];
    const float* c_v  = (const float*)d_in[3];
    const float* memp = (const float*)d_in[4];

    u32* wsu = (u32*)d_ws;
    float* wsf = (float*)((char*)d_ws + (size_t)U32_TOTAL * 4);
    // total ws use: ~7.17 MB

    auto T = [&](const void* src, long off, int N, int K, int strideU, int rowOffK, int colOff) {
        long total = (long)N * K;
        int blocks = (int)((total + 255) / 256);
        hipLaunchKernelGGL(k_transpose, dim3(blocks), dim3(256), 0, stream,
                           (const float*)src, (unsigned short*)(wsu + off), N, K, strideU, rowOffK, colOff);
    };
    T(d_in[5],  OFF_TWI,  1024, 300, 1024, 0,   0);   // t_Wi
    T(d_in[6],  OFF_TWI,  1024, 256, 1024, 300, 0);   // t_Wh
    T(d_in[8],  OFF_AWI,  256,  74,  256,  0,   0);   // a_Wi
    T(d_in[9],  OFF_AWI,  256,  64,  256,  74,  0);   // a_Wh
    T(d_in[11], OFF_VWI,  256,  36,  256,  0,   0);   // v_Wi
    T(d_in[12], OFF_VWI,  256,  64,  256,  36,  0);   // v_Wh
    T(d_in[14], OFF_A1W1, 512,  768, 512,  0,   0);   // attn1_w1
    T(d_in[16], OFF_A1W2, 768,  512, 768,  0,   0);   // attn1_w2
    T(d_in[18], OFF_A2W1, 512,  768, 512,  0,   0);   // attn2_w1
    T(d_in[20], OFF_A2W2, 256,  512, 256,  0,   0);   // attn2_w2
    T(d_in[22], OFF_GW1,  512, 1024, 1024, 0,   0);   // g1_w1 -> cols 0-511
    T(d_in[26], OFF_GW1,  512, 1024, 1024, 0,   512); // g2_w1 -> cols 512-1023
    T(d_in[24], OFF_GW2,  256,  512, 512,  0,   0);   // g1_w2 -> cols 0-255
    T(d_in[28], OFF_GW2,  256,  512, 512,  0,   256); // g2_w2 -> cols 256-511
    T(d_in[30], OFF_OW1,  512,  640, 512,  0,   0);   // out_w1

    hipLaunchKernelGGL(k_packbias, dim3(6), dim3(256), 0, stream,
                       (const float*)d_in[23], (const float*)d_in[27],
                       (const float*)d_in[25], (const float*)d_in[29], wsf);

    hipLaunchKernelGGL(fused_rnn, dim3(128), dim3(1024), 0, stream,
                       x_p, c_t, c_a, c_v, memp,
                       (const float*)d_in[7],  (const float*)d_in[10], (const float*)d_in[13],
                       (const float*)d_in[15], (const float*)d_in[17],
                       (const float*)d_in[19], (const float*)d_in[21],
                       (const float*)d_in[31], (const float*)d_in[32], (const float*)d_in[33],
                       wsu, wsf, (float*)d_out);
}

// Round 9
// 17186.079 us; speedup vs baseline: 4.3571x; 4.3389x over previous
//
#include <hip/hip_runtime.h>
#include <hip/hip_bf16.h>
#include <hip/hip_fp16.h>

typedef unsigned int u32;
typedef __fp16 h2t __attribute__((ext_vector_type(2)));

// ---------------- dims ----------------
#define T_STEPS_D 128
#define NBATCH 512

// ws layout (u32 element offsets). Weights f16, QUAD-packed:
// quad q (= k-pairs 2q,2q+1), column n: u32[q*2N + 2n + s], s = pair slot (0/1).
// A segment starting at even pair P0 begins at u32 offset P0*N.
#define OFF_TWI   0L         // pairs 278 (150 t_Wi + 128 t_Wh), N=1024
#define OFF_AWI   284672L    // pairs 70 (38 a_Wi [2 zero-pad rows] + 32 a_Wh), N=256
#define OFF_VWI   302592L    // pairs 50 (18 v_Wi + 32 v_Wh), N=256
#define OFF_A1W1  315392L    // pairs 384, N=512
#define OFF_A1W2  512000L    // pairs 256, N=768
#define OFF_A2W1  708608L    // pairs 384, N=512
#define OFF_A2W2  905216L    // pairs 256, N=256
#define OFF_GW1   970752L    // pairs 512, N=1024 (cols 0-511 g1_w1, 512-1023 g2_w1)
#define OFF_GW2   1495040L   // pairs 256, N=512 (cols 0-255 g1_w2 from z[0:512], 256-511 g2_w2 from z[512:1024])
#define OFF_OW1   1626112L   // pairs 320, N=512
#define U32_TOTAL 1789952L   // u32 elements; fp32 packed biases follow (1536 floats)

__device__ __forceinline__ float sigm(float x) { return 1.f / (1.f + __expf(-x)); }
__device__ __forceinline__ float tanh_fast(float x) {
    float e = __expf(2.f * x);
    return 1.f - 2.f / (e + 1.f);
}
__device__ __forceinline__ float dot2(u32 a, u32 b, float c) {
    union { u32 u; h2t h; } x, y; x.u = a; y.u = b;
#if __has_builtin(__builtin_amdgcn_fdot2)
    return __builtin_amdgcn_fdot2(x.h, y.h, c, false);
#else
    c += (float)x.h[0] * (float)y.h[0];
    c += (float)x.h[1] * (float)y.h[1];
    return c;
#endif
}
__device__ __forceinline__ u32 pk2(float a, float b) {
    union { h2t h; u32 u; } z;
    z.h = __builtin_amdgcn_cvt_pkrtz(a, b);
    return z.u;
}

// ---- weight block loads: one block = 8 k-pairs = 4 quads ----
__device__ __forceinline__ void gp_load1(u32* buf, const u32* __restrict__ wp, int N) {
#pragma unroll
    for (int q = 0; q < 4; ++q) {             // uint2: both pairs of this thread's column
        uint2 v = *(const uint2*)(wp + q * 2 * N);
        buf[2 * q] = v.x; buf[2 * q + 1] = v.y;
    }
}
__device__ __forceinline__ void gp_load2(u32* buf, const u32* __restrict__ wp, int N) {
#pragma unroll
    for (int q = 0; q < 4; ++q) {             // uint4: both pairs of 2 adjacent columns
        uint4 v = *(const uint4*)(wp + q * 2 * N);
        buf[4 * q] = v.x; buf[4 * q + 1] = v.y; buf[4 * q + 2] = v.z; buf[4 * q + 3] = v.w;
    }
}

// compute one block: 8 k-pairs x 4 rows x NC cols. acc has 4*NC entries (acc[NC*r+c]).
template<int NC>
__device__ __forceinline__ void gp_comp(float* acc, const u32* __restrict__ a, int stA,
                                        int kb, const u32* buf) {
#pragma unroll
    for (int r = 0; r < 4; ++r) {
        uint4 xa = *(const uint4*)(a + r * stA + kb);
        uint4 xb = *(const uint4*)(a + r * stA + kb + 4);
        u32 av[8] = {xa.x, xa.y, xa.z, xa.w, xb.x, xb.y, xb.z, xb.w};
#pragma unroll
        for (int p = 0; p < 8; ++p) {
            if constexpr (NC == 1) {
                acc[r] = dot2(buf[p], av[p], acc[r]);
            } else {
                acc[2 * r]     = dot2(buf[4 * (p >> 1) + (p & 1)],     av[p], acc[2 * r]);
                acc[2 * r + 1] = dot2(buf[4 * (p >> 1) + 2 + (p & 1)], av[p], acc[2 * r + 1]);
            }
        }
    }
}

// acc[NC*r+c] += sum_k a[r][k] * W[k][col_base+c].
// w = segment base + 2*NC*col_index (per-lane). Register prefetch pipeline, no scratch.
template<int NC, int DEPTH>
__device__ __forceinline__ void gpart(float* acc, const u32* __restrict__ a, int k2, int stA,
                                      const u32* __restrict__ w, int N)
{
    const int nb = k2 >> 3;
    u32 b0[NC * 8], b1[NC * 8], b2[NC * 8];
#define GLOAD(B, P) do { if constexpr (NC == 1) gp_load1(B, w + (long)(P) * 8 * N, N); \
                         else gp_load2(B, w + (long)(P) * 8 * N, N); } while (0)
    if (nb > 0) GLOAD(b0, 0);
    if (DEPTH > 1 && nb > 1) GLOAD(b1, 1);
    if (DEPTH > 2 && nb > 2) GLOAD(b2, 2);
    int i = 0;
    while (i < nb) {
        gp_comp<NC>(acc, a, stA, i * 8, b0);
        if (i + DEPTH < nb) GLOAD(b0, i + DEPTH);
        ++i; if (i >= nb) break;
        gp_comp<NC>(acc, a, stA, i * 8, b1);
        if (i + DEPTH < nb) GLOAD(b1, i + DEPTH);
        ++i; if (i >= nb) break;
        if (DEPTH > 2) {
            gp_comp<NC>(acc, a, stA, i * 8, b2);
            if (i + DEPTH < nb) GLOAD(b2, i + DEPTH);
            ++i;
        }
    }
#undef GLOAD
    for (int p = nb * 8; p < k2; ++p) {     // tail (<8 pairs)
        const u32* wp = w + (long)(p >> 1) * 2 * N + (p & 1);
#pragma unroll
        for (int r = 0; r < 4; ++r) {
            u32 aa = a[r * stA + p];
            if constexpr (NC == 1) {
                acc[r] = dot2(wp[0], aa, acc[r]);
            } else {
                acc[2 * r]     = dot2(wp[0], aa, acc[2 * r]);
                acc[2 * r + 1] = dot2(wp[2], aa, acc[2 * r + 1]);
            }
        }
    }
}

// -------- prologue kernels --------
__global__ void k_transpose(const float* __restrict__ src, unsigned short* __restrict__ dst,
                            int N, int K, int strideU, int rowOffK, int colOff)
{
    long i = (long)blockIdx.x * 256 + threadIdx.x;
    if (i >= (long)N * K) return;
    int n = (int)(i / K);
    int k = (int)(i - (long)n * K);
    __half h = __float2half(src[i]);
    long kk = k + rowOffK;
    long idx32 = (kk >> 2) * 2L * strideU + 2L * (colOff + n) + ((kk >> 1) & 1);
    dst[idx32 * 2 + (kk & 1)] = __half_as_ushort(h);
}

__global__ void k_packbias(const float* __restrict__ g1b1, const float* __restrict__ g2b1,
                           const float* __restrict__ g1b2, const float* __restrict__ g2b2,
                           float* __restrict__ gb)
{
    int i = blockIdx.x * 256 + threadIdx.x;
    if (i < 512) gb[i] = g1b1[i];
    else if (i < 1024) gb[i] = g2b1[i - 512];
    else if (i < 1280) gb[i] = g1b2[i - 1024];
    else if (i < 1536) gb[i] = g2b2[i - 1280];
}

// -------- main persistent kernel: one WG = 4 batch rows, 512 threads, 128 WGs --------
__global__ __launch_bounds__(512)
void fused_rnn(const float* __restrict__ x_p,
               const float* __restrict__ c_t0, const float* __restrict__ c_a0,
               const float* __restrict__ c_v0, const float* __restrict__ mem0,
               const float* __restrict__ t_b, const float* __restrict__ a_b,
               const float* __restrict__ v_b,
               const float* __restrict__ a1b1, const float* __restrict__ a1b2,
               const float* __restrict__ a2b1, const float* __restrict__ a2b2,
               const float* __restrict__ ob1, const float* __restrict__ ow2,
               const float* __restrict__ ob2,
               const u32* __restrict__ wsu, const float* __restrict__ wsf,
               float* __restrict__ out)
{
    const int tid = threadIdx.x;
    const int row0 = blockIdx.x * 4;

    // fp32 buffers
    __shared__ alignas(16) float sZ[4][1024];
    __shared__ alignas(16) float sZa[4][256];
    __shared__ alignas(16) float sZv[4][256];
    __shared__ alignas(16) float sTc[4][256];
    __shared__ alignas(16) float sAc[4][64];
    __shared__ alignas(16) float sVc[4][64];
    __shared__ alignas(16) float sM[4][256];
    __shared__ alignas(16) float sCs[4][768];
    __shared__ alignas(16) float sG[4][512];
    __shared__ alignas(16) float sCp[2][4][256];
    __shared__ alignas(16) float sHid[4][512];
    // packed f16-pair buffers
    __shared__ alignas(16) u32 pX[4][212];   // xt pairs 0-149, xa 152-189 (189=zero pad), xv 192-209
    __shared__ alignas(16) u32 pCs[4][384];
    __shared__ alignas(16) u32 pTh[4][128];
    __shared__ alignas(16) u32 pAh[4][32];
    __shared__ alignas(16) u32 pVh[4][32];
    __shared__ alignas(16) u32 pM[4][128];
    __shared__ alignas(16) u32 pHid[4][256];
    __shared__ alignas(16) u32 pZ[4][512];
    __shared__ float sRed[4];
    __shared__ float sRed2[8][4];

    // ---- init states ----
    for (int i = tid; i < 4 * 128; i += 512) {
        int r = i >> 7, j2 = i & 127, j = 2 * j2;
        float t0 = c_t0[(row0 + r) * 256 + j], t1 = c_t0[(row0 + r) * 256 + j + 1];
        float m0 = mem0[(row0 + r) * 256 + j], m1 = mem0[(row0 + r) * 256 + j + 1];
        sTc[r][j] = t0; sTc[r][j + 1] = t1;
        sM[r][j] = m0; sM[r][j + 1] = m1;
        pM[r][j2] = pk2(m0, m1);
        pTh[r][j2] = 0u;
    }
    for (int i = tid; i < 4 * 32; i += 512) {
        int r = i >> 5, j2 = i & 31, j = 2 * j2;
        sAc[r][j] = c_a0[(row0 + r) * 64 + j]; sAc[r][j + 1] = c_a0[(row0 + r) * 64 + j + 1];
        sVc[r][j] = c_v0[(row0 + r) * 64 + j]; sVc[r][j + 1] = c_v0[(row0 + r) * 64 + j + 1];
        pAh[r][j2] = 0u; pVh[r][j2] = 0u;
    }
    if (tid < 12) pX[tid / 3][189 + tid % 3] = 0u;   // zero pad pair for a-LSTM
    __syncthreads();

    for (int t = 0; t < T_STEPS_D; ++t) {
        // ---- stage 1: pack x, copy+pack pre_c ----
        const float* xb = x_p + ((long)t * NBATCH + row0) * 410;
        for (int i = tid; i < 4 * 205; i += 512) {
            int r = i / 205, p = i - r * 205;
            float2 v = *(const float2*)(xb + r * 410 + 2 * p);
            int dst = (p < 150) ? p : (p < 187 ? p + 2 : p + 5);
            pX[r][dst] = pk2(v.x, v.y);
        }
        for (int i = tid; i < 4 * 192; i += 512) {
            int r = i / 192, p = i - r * 192;
            float v0, v1; int c;
            if (p < 128) { c = 2 * p; v0 = sTc[r][c]; v1 = sTc[r][c + 1]; }
            else if (p < 160) { int j = 2 * (p - 128); c = 256 + j; v0 = sAc[r][j]; v1 = sAc[r][j + 1]; }
            else { int j = 2 * (p - 160); c = 320 + j; v0 = sVc[r][j]; v1 = sVc[r][j + 1]; }
            sCs[r][c] = v0; sCs[r][c + 1] = v1;
            pCs[r][p] = pk2(v0, v1);
        }
        __syncthreads();

        // ---- stage 2: LSTM pre-activations ----
        {   // t-LSTM: N=1024, NC=2, cols 2tid,2tid+1
            float acc[8] = {0.f, 0.f, 0.f, 0.f, 0.f, 0.f, 0.f, 0.f};
            gpart<2, 2>(acc, &pX[0][0], 150, 212, wsu + OFF_TWI + 4 * tid, 1024);
            gpart<2, 2>(acc, &pTh[0][0], 128, 128, wsu + OFF_TWI + 150L * 1024 + 4 * tid, 1024);
            float bb0 = t_b[2 * tid], bb1 = t_b[2 * tid + 1];
#pragma unroll
            for (int r = 0; r < 4; ++r) {
                sZ[r][2 * tid] = acc[2 * r] + bb0;
                sZ[r][2 * tid + 1] = acc[2 * r + 1] + bb1;
            }
        }
        if (tid < 256) {   // a-LSTM (38 pairs incl. zero pad)
            float acc[4] = {0.f, 0.f, 0.f, 0.f};
            gpart<1, 3>(acc, &pX[0][152], 38, 212, wsu + OFF_AWI + 2 * tid, 256);
            gpart<1, 3>(acc, &pAh[0][0], 32, 32, wsu + OFF_AWI + 38L * 256 + 2 * tid, 256);
            float b = a_b[tid];
#pragma unroll
            for (int r = 0; r < 4; ++r) sZa[r][tid] = acc[r] + b;
        } else {           // v-LSTM
            int st = tid - 256;
            float acc[4] = {0.f, 0.f, 0.f, 0.f};
            gpart<1, 3>(acc, &pX[0][192], 18, 212, wsu + OFF_VWI + 2 * st, 256);
            gpart<1, 3>(acc, &pVh[0][0], 32, 32, wsu + OFF_VWI + 18L * 256 + 2 * st, 256);
            float b = v_b[st];
#pragma unroll
            for (int r = 0; r < 4; ++r) sZv[r][st] = acc[r] + b;
        }
        __syncthreads();

        // ---- stage 3: LSTM pointwise ----
        {
            int j = tid & 255;
            for (int r = tid >> 8; r < 4; r += 2) {
                float iv = sZ[r][j], fv = sZ[r][256 + j], gv = sZ[r][512 + j], ov = sZ[r][768 + j];
                float c2 = sigm(fv) * sTc[r][j] + sigm(iv) * tanh_fast(gv);
                float h2 = sigm(ov) * tanh_fast(c2);
                sTc[r][j] = c2; sCs[r][384 + j] = c2;
                // pack pairs: j even lane packs (j, j+1) via shfl
                float c2o = __shfl_xor(c2, 1), h2o = __shfl_xor(h2, 1);
                if (!(j & 1)) {
                    pTh[r][j >> 1] = pk2(h2, h2o);
                    pCs[r][192 + (j >> 1)] = pk2(c2, c2o);
                }
            }
            int cell = tid >> 8, r2 = (tid >> 6) & 3, j2 = tid & 63;
            if (cell == 0) {
                float iv = sZa[r2][j2], fv = sZa[r2][64 + j2], gv = sZa[r2][128 + j2], ov = sZa[r2][192 + j2];
                float c2 = sigm(fv) * sAc[r2][j2] + sigm(iv) * tanh_fast(gv);
                float h2 = sigm(ov) * tanh_fast(c2);
                sAc[r2][j2] = c2; sCs[r2][640 + j2] = c2;
                float c2o = __shfl_xor(c2, 1), h2o = __shfl_xor(h2, 1);
                if (!(j2 & 1)) {
                    pAh[r2][j2 >> 1] = pk2(h2, h2o);
                    pCs[r2][320 + (j2 >> 1)] = pk2(c2, c2o);
                }
            } else {
                float iv = sZv[r2][j2], fv = sZv[r2][64 + j2], gv = sZv[r2][128 + j2], ov = sZv[r2][192 + j2];
                float c2 = sigm(fv) * sVc[r2][j2] + sigm(iv) * tanh_fast(gv);
                float h2 = sigm(ov) * tanh_fast(c2);
                sVc[r2][j2] = c2; sCs[r2][704 + j2] = c2;
                float c2o = __shfl_xor(c2, 1), h2o = __shfl_xor(h2, 1);
                if (!(j2 & 1)) {
                    pVh[r2][j2 >> 1] = pk2(h2, h2o);
                    pCs[r2][352 + (j2 >> 1)] = pk2(c2, c2o);
                }
            }
        }
        __syncthreads();

        // ---- stage 4a: attn1-l1 (N=512, NC=1, relu, pack via shfl) ----
        {
            float acc[4] = {0.f, 0.f, 0.f, 0.f};
            gpart<1, 3>(acc, &pCs[0][0], 384, 384, wsu + OFF_A1W1 + 2 * tid, 512);
            float b = a1b1[tid];
#pragma unroll
            for (int r = 0; r < 4; ++r) {
                float v = fmaxf(acc[r] + b, 0.f);
                float vo = __shfl_xor(v, 1);
                if (!(tid & 1)) pHid[r][tid >> 1] = pk2(v, vo);
            }
        }
        __syncthreads();
        // ---- stage 4b: attn1-l2 (N=768, NC=2 on 384 threads) ----
        if (tid < 384) {
            float acc[8] = {0.f, 0.f, 0.f, 0.f, 0.f, 0.f, 0.f, 0.f};
            gpart<2, 2>(acc, &pHid[0][0], 256, 256, wsu + OFF_A1W2 + 4 * tid, 768);
            float bb0 = a1b2[2 * tid], bb1 = a1b2[2 * tid + 1];
#pragma unroll
            for (int r = 0; r < 4; ++r) {
                sZ[r][2 * tid] = acc[2 * r] + bb0;
                sZ[r][2 * tid + 1] = acc[2 * r + 1] + bb1;
            }
        }
        __syncthreads();

        // ---- stage 5: softmax + attended -> pCs ----
        {
            int wv = tid >> 6, ln = tid & 63;
            if (wv < 4) {
                float mx = -3.0e38f;
                for (int i = ln; i < 768; i += 64) mx = fmaxf(mx, sZ[wv][i]);
                for (int o = 32; o; o >>= 1) mx = fmaxf(mx, __shfl_xor(mx, o));
                float sum = 0.f;
                for (int i = ln; i < 768; i += 64) { float e = __expf(sZ[wv][i] - mx); sZ[wv][i] = e; sum += e; }
                for (int o = 32; o; o >>= 1) sum += __shfl_xor(sum, o);
                if (ln == 0) sRed[wv] = 1.f / sum;
            }
        }
        __syncthreads();
        for (int i = tid; i < 4 * 384; i += 512) {
            int r = i / 384, p = i - r * 384, c = 2 * p;
            float s = sRed[r];
            pCs[r][p] = pk2(sZ[r][c] * s * sCs[r][c], sZ[r][c + 1] * s * sCs[r][c + 1]);
        }
        __syncthreads();

        // ---- stage 6: attn2-l1 -> pHid ; gates-l1 -> pZ (disjoint outputs) ----
        {
            float acc[4] = {0.f, 0.f, 0.f, 0.f};
            gpart<1, 3>(acc, &pCs[0][0], 384, 384, wsu + OFF_A2W1 + 2 * tid, 512);
            float b = a2b1[tid];
#pragma unroll
            for (int r = 0; r < 4; ++r) {
                float v = fmaxf(acc[r] + b, 0.f);
                float vo = __shfl_xor(v, 1);
                if (!(tid & 1)) pHid[r][tid >> 1] = pk2(v, vo);
            }
        }
        {
            float acc[8] = {0.f, 0.f, 0.f, 0.f, 0.f, 0.f, 0.f, 0.f};
            gpart<2, 2>(acc, &pCs[0][0], 384, 384, wsu + OFF_GW1 + 4 * tid, 1024);
            gpart<2, 2>(acc, &pM[0][0], 128, 128, wsu + OFF_GW1 + 384L * 1024 + 4 * tid, 1024);
            float bb0 = wsf[2 * tid], bb1 = wsf[2 * tid + 1];
#pragma unroll
            for (int r = 0; r < 4; ++r) {
                float v0 = fmaxf(acc[2 * r] + bb0, 0.f);
                float v1 = fmaxf(acc[2 * r + 1] + bb1, 0.f);
                pZ[r][tid] = pk2(v0, v1);   // cols 2tid,2tid+1 = pair tid
            }
        }
        __syncthreads();

        // ---- stage 7: gates-l2 (col=tid, act half by col) ; attn2-l2 split-K ----
        {
            float acc[4] = {0.f, 0.f, 0.f, 0.f};
            gpart<1, 3>(acc, &pZ[0][(tid >> 8) * 256], 256, 512, wsu + OFF_GW2 + 2 * tid, 512);
            float b = wsf[1024 + tid];
#pragma unroll
            for (int r = 0; r < 4; ++r) sG[r][tid] = acc[r] + b;
        }
        {
            int kh = tid >> 8, col = tid & 255;
            float acc[4] = {0.f, 0.f, 0.f, 0.f};
            gpart<1, 3>(acc, &pHid[0][kh * 128], 128, 256,
                        wsu + OFF_A2W2 + (long)kh * 128 * 256 + 2 * col, 256);
#pragma unroll
            for (int r = 0; r < 4; ++r) sCp[kh][r][col] = acc[r];
        }
        __syncthreads();

        // ---- stage 8: memory update ----
        {
            int j = tid & 255;
            for (int r = tid >> 8; r < 4; r += 2) {
                float g1v = sigm(sG[r][j]);
                float g2v = sigm(sG[r][256 + j]);
                float ch = tanh_fast(sCp[0][r][j] + sCp[1][r][j] + a2b2[j]);
                float m2 = g1v * sM[r][j] + g2v * ch;
                sM[r][j] = m2;
                float m2o = __shfl_xor(m2, 1);
                if (!(j & 1)) pM[r][j >> 1] = pk2(m2, m2o);
            }
        }
        __syncthreads();
    }

    // ---- output head: last_h = [th, ah, vh, m] ----
    {
        float acc[4] = {0.f, 0.f, 0.f, 0.f};
        gpart<1, 3>(acc, &pTh[0][0], 128, 128, wsu + OFF_OW1 + 2 * tid, 512);
        gpart<1, 3>(acc, &pAh[0][0], 32, 32, wsu + OFF_OW1 + 128L * 512 + 2 * tid, 512);
        gpart<1, 3>(acc, &pVh[0][0], 32, 32, wsu + OFF_OW1 + 160L * 512 + 2 * tid, 512);
        gpart<1, 3>(acc, &pM[0][0], 128, 128, wsu + OFF_OW1 + 192L * 512 + 2 * tid, 512);
        float b = ob1[tid];
#pragma unroll
        for (int r = 0; r < 4; ++r) sHid[r][tid] = fmaxf(acc[r] + b, 0.f);
    }
    __syncthreads();
    {
        float wv2 = ow2[tid];
        float pr[4];
#pragma unroll
        for (int r = 0; r < 4; ++r) pr[r] = sHid[r][tid] * wv2;
#pragma unroll
        for (int o = 32; o; o >>= 1) {
#pragma unroll
            for (int r = 0; r < 4; ++r) pr[r] += __shfl_xor(pr[r], o);
        }
        int wvid = tid >> 6, ln = tid & 63;
        if (ln == 0) {
#pragma unroll
            for (int r = 0; r < 4; ++r) sRed2[wvid][r] = pr[r];
        }
        __syncthreads();
        if (tid < 4) {
            float s = 0.f;
#pragma unroll
            for (int w = 0; w < 8; ++w) s += sRed2[w][tid];
            out[row0 + tid] = s + ob2[0];
        }
    }
}

extern "C" void kernel_launch(void* const* d_in, const int* in_sizes, int n_in,
                              void* d_out, int out_size, void* d_ws, size_t ws_size,
                              hipStream_t stream)
{
    const float* x_p  = (const float*)d_in[0];
    const float* c_t  = (const float*)d_in[1];
    const float* c_a  = (const float*)d_in[2];
    const float* c_v  = (const float*)d_in[3];
    const float* memp = (const float*)d_in[4];

    u32* wsu = (u32*)d_ws;
    float* wsf = (float*)((char*)d_ws + (size_t)U32_TOTAL * 4);
    // total ws use: ~7.17 MB

    // zero the AWI region (covers a_Wi's 2 zero-pad k-rows)
    hipMemsetAsync((char*)d_ws + (size_t)OFF_AWI * 4, 0, (size_t)(OFF_VWI - OFF_AWI) * 4, stream);

    auto T = [&](const void* src, long off, int N, int K, int strideU, int rowOffK, int colOff) {
        long total = (long)N * K;
        int blocks = (int)((total + 255) / 256);
        hipLaunchKernelGGL(k_transpose, dim3(blocks), dim3(256), 0, stream,
                           (const float*)src, (unsigned short*)(wsu + off), N, K, strideU, rowOffK, colOff);
    };
    T(d_in[5],  OFF_TWI,  1024, 300, 1024, 0,   0);   // t_Wi   (k 0..299)
    T(d_in[6],  OFF_TWI,  1024, 256, 1024, 300, 0);   // t_Wh   (k 300..555)
    T(d_in[8],  OFF_AWI,  256,  74,  256,  0,   0);   // a_Wi   (k 0..73; 74,75 zero pad)
    T(d_in[9],  OFF_AWI,  256,  64,  256,  76,  0);   // a_Wh   (k 76..139)
    T(d_in[11], OFF_VWI,  256,  36,  256,  0,   0);   // v_Wi
    T(d_in[12], OFF_VWI,  256,  64,  256,  36,  0);   // v_Wh
    T(d_in[14], OFF_A1W1, 512,  768, 512,  0,   0);   // attn1_w1
    T(d_in[16], OFF_A1W2, 768,  512, 768,  0,   0);   // attn1_w2
    T(d_in[18], OFF_A2W1, 512,  768, 512,  0,   0);   // attn2_w1
    T(d_in[20], OFF_A2W2, 256,  512, 256,  0,   0);   // attn2_w2
    T(d_in[22], OFF_GW1,  512, 1024, 1024, 0,   0);   // g1_w1 -> cols 0-511
    T(d_in[26], OFF_GW1,  512, 1024, 1024, 0,   512); // g2_w1 -> cols 512-1023
    T(d_in[24], OFF_GW2,  256,  512, 512,  0,   0);   // g1_w2 -> cols 0-255
    T(d_in[28], OFF_GW2,  256,  512, 512,  0,   256); // g2_w2 -> cols 256-511
    T(d_in[30], OFF_OW1,  512,  640, 512,  0,   0);   // out_w1

    hipLaunchKernelGGL(k_packbias, dim3(6), dim3(256), 0, stream,
                       (const float*)d_in[23], (const float*)d_in[27],
                       (const float*)d_in[25], (const float*)d_in[29], wsf);

    hipLaunchKernelGGL(fused_rnn, dim3(128), dim3(512), 0, stream,
                       x_p, c_t, c_a, c_v, memp,
                       (const float*)d_in[7],  (const float*)d_in[10], (const float*)d_in[13],
                       (const float*)d_in[15], (const float*)d_in[17],
                       (const float*)d_in[19], (const float*)d_in[21],
                       (const float*)d_in[31], (const float*)d_in[32], (const float*)d_in[33],
                       wsu, wsf, (float*)d_out);
}